// Round 2
// baseline (930.896 us; speedup 1.0000x reference)
//
#include <hip/hip_runtime.h>

#define DM 256
#define HH 4
#define DH 64
#define BB 8
#define NN 2048

typedef short bf16x8 __attribute__((ext_vector_type(8)));   // 8 bf16 in 4 VGPRs
typedef float f32x4  __attribute__((ext_vector_type(4)));

__device__ inline unsigned short f2bf(float f) {
  unsigned int u = __float_as_uint(f);
  u += 0x7fffu + ((u >> 16) & 1u);           // round-to-nearest-even
  return (unsigned short)(u >> 16);
}
// pack 8 consecutive fp32 -> bf16x8 (two float4 loads, 32B-aligned callers only)
__device__ inline bf16x8 cvt8(const float* __restrict__ p) {
  float4 a = *(const float4*)p;
  float4 b = *(const float4*)(p + 4);
  bf16x8 r;
  r[0] = (short)f2bf(a.x); r[1] = (short)f2bf(a.y);
  r[2] = (short)f2bf(a.z); r[3] = (short)f2bf(a.w);
  r[4] = (short)f2bf(b.x); r[5] = (short)f2bf(b.y);
  r[6] = (short)f2bf(b.z); r[7] = (short)f2bf(b.w);
  return r;
}
#define MFMA(a, b, c) __builtin_amdgcn_mfma_f32_16x16x32_bf16((a), (b), (c), 0, 0, 0)

// ---------------------------------------------------------------------------
// Kernel 0: fp32 weights -> bf16.  th<16: transpose per-head W [H,256,64] ->
// WT[t][h][64][256].  th>=16: straight-convert Wo chunk (already B-frag order).
// ---------------------------------------------------------------------------
__global__ void k_wtrans(const float* __restrict__ Wq, const float* __restrict__ Wk,
                         const float* __restrict__ Wv, const float* __restrict__ Wr,
                         const float* __restrict__ Wo,
                         unsigned short* __restrict__ WT,
                         unsigned short* __restrict__ WoB) {
  int th = blockIdx.x;
  if (th < 16) {
    int t = th >> 2, h = th & 3;
    const float* W =
        (t == 0 ? Wq : t == 1 ? Wk : t == 2 ? Wv : Wr) + (size_t)h * DM * DH;
    unsigned short* O = WT + (size_t)th * DH * DM;
    for (int idx = threadIdx.x; idx < DM * DH; idx += blockDim.x) {
      int k = idx >> 6, n = idx & 63;
      O[n * DM + k] = f2bf(W[idx]);
    }
  } else {
    int c = th - 16;                       // 0..3, 16384 elements each
    for (int idx = threadIdx.x; idx < 16384; idx += blockDim.x)
      WoB[c * 16384 + idx] = f2bf(Wo[c * 16384 + idx]);
  }
}

// ---------------------------------------------------------------------------
// Kernel 1: projections. t=0: q = Q@Wq+bq   t=1: kr = K@Wk+bk + R@Wr+br
//           t=2: v = V@Wv+bv stored TRANSPOSED as vT[bh][d][n]
// q, kr: [bh][n][64] bf16.  One block = 64 rows x 64 dims, wave = 16 rows.
// ---------------------------------------------------------------------------
__launch_bounds__(256)
__global__ void k_proj(const float* __restrict__ Q, const float* __restrict__ K,
                       const float* __restrict__ V, const float* __restrict__ R,
                       const unsigned short* __restrict__ WT,
                       const float* __restrict__ bq, const float* __restrict__ bk,
                       const float* __restrict__ bv, const float* __restrict__ br,
                       unsigned short* __restrict__ qd,
                       unsigned short* __restrict__ krd,
                       unsigned short* __restrict__ vTd) {
  int id = blockIdx.x;
  int ntile = id & 31; id >>= 5;
  int h = id & 3;      id >>= 2;
  int b = id & 7;      id >>= 3;
  int t = id;                       // 0=q,1=kr,2=v
  int wave = threadIdx.x >> 6, lane = threadIdx.x & 63;
  int lm = lane & 15, quad = lane >> 4;
  int row0 = ntile * 64 + wave * 16;

  f32x4 acc[4];
#pragma unroll
  for (int nt = 0; nt < 4; ++nt) acc[nt] = f32x4{0.f, 0.f, 0.f, 0.f};

  auto pass = [&](const float* X, const unsigned short* Wt) {
    const float* xrow = X + ((size_t)b * NN + row0 + lm) * DM;
#pragma unroll
    for (int ks = 0; ks < 8; ++ks) {
      bf16x8 a = cvt8(xrow + ks * 32 + quad * 8);
#pragma unroll
      for (int nt = 0; nt < 4; ++nt) {
        bf16x8 bf = *(const bf16x8*)(Wt + (size_t)(nt * 16 + lm) * DM + ks * 32 + quad * 8);
        acc[nt] = MFMA(a, bf, acc[nt]);
      }
    }
  };

  if (t == 0) {
    pass(Q, WT + (size_t)(0 * 4 + h) * DH * DM);
  } else if (t == 1) {
    pass(K, WT + (size_t)(1 * 4 + h) * DH * DM);
    pass(R, WT + (size_t)(3 * 4 + h) * DH * DM);
  } else {
    pass(V, WT + (size_t)(2 * 4 + h) * DH * DM);
  }

  size_t bh = (size_t)b * HH + h;
  if (t == 2) {
    // vT[bh][d][n]: lane holds 4 consecutive n for one d -> 8B packed store
#pragma unroll
    for (int nt = 0; nt < 4; ++nt) {
      int d = nt * 16 + lm;
      float bias = bv[h * DH + d];
      ushort4 pk;
      pk.x = f2bf(acc[nt][0] + bias);
      pk.y = f2bf(acc[nt][1] + bias);
      pk.z = f2bf(acc[nt][2] + bias);
      pk.w = f2bf(acc[nt][3] + bias);
      *(ushort4*)(vTd + bh * DH * NN + (size_t)d * NN + row0 + quad * 4) = pk;
    }
  } else {
    unsigned short* dst = (t == 0 ? qd : krd) + bh * NN * DH;
#pragma unroll
    for (int nt = 0; nt < 4; ++nt) {
      int d = nt * 16 + lm;
      float bias = (t == 0) ? bq[h * DH + d] : bk[h * DH + d] + br[h * DH + d];
#pragma unroll
      for (int i = 0; i < 4; ++i)
        dst[(size_t)(row0 + quad * 4 + i) * DH + d] = f2bf(acc[nt][i] + bias);
    }
  }
}

// ---------------------------------------------------------------------------
// Kernel 2: flash attention + fp32 raw-score writeout.
// Block = 64 Q rows of one (b,h); wave = 16 rows, loops 2048 cols in 32-chunks.
// ---------------------------------------------------------------------------
__launch_bounds__(256)
__global__ void k_attn(const unsigned short* __restrict__ qd,
                       const unsigned short* __restrict__ krd,
                       const unsigned short* __restrict__ vTd,
                       float* __restrict__ scores,
                       unsigned short* __restrict__ xd) {
  __shared__ unsigned short pst[4][2][16 * 32];   // per-wave, double-buffered
  int id = blockIdx.x;
  int qt = id & 31; id >>= 5;
  int h = id & 3;   id >>= 2;
  int b = id;
  size_t bh = (size_t)b * HH + h;
  int wave = threadIdx.x >> 6, lane = threadIdx.x & 63;
  int lm = lane & 15, quad = lane >> 4;
  int qrow = qt * 64 + wave * 16;
  const float L2E = 1.4426950408889634f;

  const unsigned short* qrp = qd + (bh * NN + qrow + lm) * DH;
  bf16x8 aq0 = *(const bf16x8*)(qrp + quad * 8);
  bf16x8 aq1 = *(const bf16x8*)(qrp + 32 + quad * 8);

  f32x4 oacc[4];
#pragma unroll
  for (int nt = 0; nt < 4; ++nt) oacc[nt] = f32x4{0.f, 0.f, 0.f, 0.f};
  float mi[4] = {-INFINITY, -INFINITY, -INFINITY, -INFINITY};
  float li[4] = {0.f, 0.f, 0.f, 0.f};

  const unsigned short* krb = krd + bh * NN * DH;
  const unsigned short* vtb = vTd + bh * DH * NN;
  float* sb = scores + bh * (size_t)NN * NN + (size_t)qrow * NN;

  for (int c = 0; c < NN; c += 32) {
    // ---- S = q . kr^T for 32 columns (2 n-tiles) ----
    const unsigned short* k0 = krb + (size_t)(c + lm) * DH + quad * 8;
    const unsigned short* k1 = krb + (size_t)(c + 16 + lm) * DH + quad * 8;
    f32x4 s0 = f32x4{0.f, 0.f, 0.f, 0.f}, s1 = f32x4{0.f, 0.f, 0.f, 0.f};
    s0 = MFMA(aq0, *(const bf16x8*)(k0), s0);
    s0 = MFMA(aq1, *(const bf16x8*)(k0 + 32), s0);
    s1 = MFMA(aq0, *(const bf16x8*)(k1), s1);
    s1 = MFMA(aq1, *(const bf16x8*)(k1 + 32), s1);
#pragma unroll
    for (int i = 0; i < 4; ++i) { s0[i] *= 0.125f; s1[i] *= 0.125f; }

    // ---- raw scaled scores out (fp32) ----
#pragma unroll
    for (int i = 0; i < 4; ++i) {
      sb[(size_t)(quad * 4 + i) * NN + c + lm]      = s0[i];
      sb[(size_t)(quad * 4 + i) * NN + c + 16 + lm] = s1[i];
    }

    // ---- online softmax ----
    float al[4];
#pragma unroll
    for (int i = 0; i < 4; ++i) {
      float t = fmaxf(s0[i], s1[i]);
      t = fmaxf(t, __shfl_xor(t, 1));
      t = fmaxf(t, __shfl_xor(t, 2));
      t = fmaxf(t, __shfl_xor(t, 4));
      t = fmaxf(t, __shfl_xor(t, 8));
      float mn = fmaxf(mi[i], t);
      al[i] = exp2f((mi[i] - mn) * L2E);
      mi[i] = mn;
      float p0 = exp2f((s0[i] - mn) * L2E);
      float p1 = exp2f((s1[i] - mn) * L2E);
      li[i] = li[i] * al[i] + p0 + p1;
      s0[i] = p0; s1[i] = p1;
    }
#pragma unroll
    for (int nt = 0; nt < 4; ++nt)
#pragma unroll
      for (int i = 0; i < 4; ++i) oacc[nt][i] *= al[i];

    // ---- P: C-layout -> A-layout via wave-private LDS ----
    unsigned short* ps = pst[wave][(c >> 5) & 1];
#pragma unroll
    for (int i = 0; i < 4; ++i) {
      ps[(quad * 4 + i) * 32 + lm]      = f2bf(s0[i]);
      ps[(quad * 4 + i) * 32 + 16 + lm] = f2bf(s1[i]);
    }
    asm volatile("s_waitcnt lgkmcnt(0)" ::: "memory");
    bf16x8 ap = *(const bf16x8*)(ps + lm * 32 + quad * 8);

    // ---- O += P @ V ----
#pragma unroll
    for (int nt = 0; nt < 4; ++nt) {
      bf16x8 bv = *(const bf16x8*)(vtb + (size_t)(nt * 16 + lm) * NN + c + quad * 8);
      oacc[nt] = MFMA(ap, bv, oacc[nt]);
    }
  }

  // ---- finalize: divide by row sums, write x[b][n][h*64+d] (bf16) ----
  float linv[4];
#pragma unroll
  for (int i = 0; i < 4; ++i) {
    float t = li[i];
    t += __shfl_xor(t, 1);
    t += __shfl_xor(t, 2);
    t += __shfl_xor(t, 4);
    t += __shfl_xor(t, 8);
    linv[i] = 1.f / t;
  }
  unsigned short* xb = xd + ((size_t)b * NN + qrow) * DM + h * DH;
#pragma unroll
  for (int nt = 0; nt < 4; ++nt)
#pragma unroll
    for (int i = 0; i < 4; ++i)
      xb[(size_t)(quad * 4 + i) * DM + nt * 16 + lm] = f2bf(oacc[nt][i] * linv[i]);
}

// ---------------------------------------------------------------------------
// Kernel 3: out = x @ Wo^T + bo (fp32 out).  WoB bf16 [out,in] is already
// B-fragment-contiguous. Block = 64 rows x 64 out-cols.
// ---------------------------------------------------------------------------
__launch_bounds__(256)
__global__ void k_oproj(const unsigned short* __restrict__ xd,
                        const unsigned short* __restrict__ WoB,
                        const float* __restrict__ bo,
                        float* __restrict__ outd) {
  int id = blockIdx.x;
  int ot = id & 3;     id >>= 2;
  int ntile = id & 31; id >>= 5;
  int b = id;
  int wave = threadIdx.x >> 6, lane = threadIdx.x & 63;
  int lm = lane & 15, quad = lane >> 4;
  int row0 = ntile * 64 + wave * 16;

  const unsigned short* xrow = xd + ((size_t)b * NN + row0 + lm) * DM;
  f32x4 acc[4];
#pragma unroll
  for (int nt = 0; nt < 4; ++nt) acc[nt] = f32x4{0.f, 0.f, 0.f, 0.f};

#pragma unroll
  for (int ks = 0; ks < 8; ++ks) {
    bf16x8 a = *(const bf16x8*)(xrow + ks * 32 + quad * 8);
#pragma unroll
    for (int nt = 0; nt < 4; ++nt) {
      int o = ot * 64 + nt * 16 + lm;
      bf16x8 bf = *(const bf16x8*)(WoB + (size_t)o * DM + ks * 32 + quad * 8);
      acc[nt] = MFMA(a, bf, acc[nt]);
    }
  }
#pragma unroll
  for (int nt = 0; nt < 4; ++nt) {
    int o = ot * 64 + nt * 16 + lm;
    float bias = bo[o];
#pragma unroll
    for (int i = 0; i < 4; ++i)
      outd[((size_t)b * NN + row0 + quad * 4 + i) * DM + o] = acc[nt][i] + bias;
  }
}

// ---------------------------------------------------------------------------
extern "C" void kernel_launch(void* const* d_in, const int* in_sizes, int n_in,
                              void* d_out, int out_size, void* d_ws, size_t ws_size,
                              hipStream_t stream) {
  const float* Q  = (const float*)d_in[0];
  const float* K  = (const float*)d_in[1];
  const float* V  = (const float*)d_in[2];
  const float* R  = (const float*)d_in[3];
  const float* Wq = (const float*)d_in[4];
  const float* bq = (const float*)d_in[5];
  const float* Wk = (const float*)d_in[6];
  const float* bk = (const float*)d_in[7];
  const float* Wv = (const float*)d_in[8];
  const float* bv = (const float*)d_in[9];
  const float* Wr = (const float*)d_in[10];
  const float* br = (const float*)d_in[11];
  const float* Wo = (const float*)d_in[12];
  const float* bo = (const float*)d_in[13];

  float* outd   = (float*)d_out;
  float* scores = outd + (size_t)BB * NN * DM;   // out first, then scores

  char* ws = (char*)d_ws;
  unsigned short* WT  = (unsigned short*)ws;                      // 512 KB
  unsigned short* WoB = (unsigned short*)(ws + (512 << 10));      // 128 KB
  unsigned short* qd  = (unsigned short*)(ws + (1 << 20));        // 8 MB
  unsigned short* krd = (unsigned short*)(ws + (9 << 20));        // 8 MB
  unsigned short* vTd = (unsigned short*)(ws + (17 << 20));       // 8 MB
  unsigned short* xd  = (unsigned short*)(ws + (25 << 20));       // 8 MB

  k_wtrans<<<dim3(20), dim3(256), 0, stream>>>(Wq, Wk, Wv, Wr, Wo, WT, WoB);
  k_proj<<<dim3(3 * BB * HH * (NN / 64)), dim3(256), 0, stream>>>(
      Q, K, V, R, WT, bq, bk, bv, br, qd, krd, vTd);
  k_attn<<<dim3(BB * HH * (NN / 64)), dim3(256), 0, stream>>>(
      qd, krd, vTd, scores, xd);
  k_oproj<<<dim3(BB * (NN / 64) * 4), dim3(256), 0, stream>>>(xd, WoB, bo, outd);
}